// Round 1
// baseline (1690.831 us; speedup 1.0000x reference)
//
#include <hip/hip_runtime.h>
#include <hip/hip_bf16.h>

// Problem constants (from reference): B=8, S=512 -> TOK=4096 tokens,
// D=1024, F=2048, H=16 heads, V=3000, O=1.
#define TOK 4096
#define DD  1024
#define FF  2048
#define NH  16

// jax.nn.gelu(approximate=True): 0.5*x*(1+tanh(sqrt(2/pi)*(x+0.044715 x^3)))
// tanh via exp, written in the overflow-robust form t = 1 - 2/(e^{2u}+1).
__device__ __forceinline__ float gelu_f(float x) {
  float u = 0.7978845608028654f * (x + 0.044715f * x * x * x);
  float e = __expf(2.0f * u);
  return 0.5f * x * (2.0f - 2.0f / (e + 1.0f));
}

// ---------------------------------------------------------------------------
// Routing: head = task-1 (task>0), invalid -> -1. Builds per-head token lists
// and initializes d_out (b2[h] for valid tokens -- stage2 atomically adds the
// rest; 0 for invalid tokens). counts[] must be zeroed before this kernel.
// ---------------------------------------------------------------------------
__global__ __launch_bounds__(256) void route_kernel(
    const int* __restrict__ tasks, const float* __restrict__ b2,
    int* __restrict__ counts, int* __restrict__ lists, float* __restrict__ out) {
  int t = blockIdx.x * 256 + threadIdx.x;
  if (t >= TOK) return;
  int task = tasks[t];
  if (task > 0) {
    int h = (task - 1) & (NH - 1);
    int pos = atomicAdd(&counts[h], 1);
    lists[h * TOK + pos] = t;
    out[t] = b2[h];
  } else {
    out[t] = 0.0f;
  }
}

// ---------------------------------------------------------------------------
// Stage 1: shared = gelu(h @ Ws + bs), h built on the fly from embeddings
// (fused -- h is never materialized). M=4096, N=K=1024. 64x64 tile, BK=16,
// 256 threads, 4x4 microtile per thread.
// ---------------------------------------------------------------------------
__global__ __launch_bounds__(256) void gemm1_kernel(
    const int* __restrict__ selfies, const int* __restrict__ tasks,
    const float* __restrict__ values, const int* __restrict__ pmask,
    const float* __restrict__ emb_s, const float* __restrict__ emb_t,
    const float* __restrict__ val_vec, const float* __restrict__ Ws,
    const float* __restrict__ bs, float* __restrict__ shared_out) {
  __shared__ float As[16][64];   // [k][m] (transposed store)
  __shared__ float Bs[16][64];   // [k][n]
  __shared__ int   ssid[64];
  __shared__ int   stsk[64];
  __shared__ float sval[64];
  __shared__ float smsk[64];

  const int tid = threadIdx.x;
  const int m0 = blockIdx.x * 64;
  const int n0 = blockIdx.y * 64;

  if (tid < 64) {
    int t = m0 + tid;
    ssid[tid] = selfies[t];
    stsk[tid] = tasks[t];
    sval[tid] = values[t];
    smsk[tid] = pmask[t] ? 1.0f : 0.0f;
  }
  __syncthreads();

  // A-staging role: 64 rows x 16 k, float4 along k.
  const int arow = tid >> 2;          // 0..63
  const int akc  = (tid & 3) << 2;    // 0,4,8,12
  const int   sid = ssid[arow];
  const int   tsk = stsk[arow];
  const float v   = sval[arow];
  const float msk = smsk[arow];
  const float* pa_s = emb_s + (size_t)sid * DD;
  const float* pa_t = emb_t + (size_t)tsk * DD;

  // B-staging role: 16 k-rows x 64 n, float4 along n.
  const int bk = tid >> 4;            // 0..15
  const int bn = (tid & 15) << 2;     // 0..60

  const int ty = tid >> 4;            // 0..15 (row group)
  const int tx = tid & 15;            // 0..15 (col group)

  float acc[4][4] = {};

  for (int k0 = 0; k0 < DD; k0 += 16) {
    float4 a = *(const float4*)(pa_s + k0 + akc);
    float4 b = *(const float4*)(pa_t + k0 + akc);
    float4 c = *(const float4*)(val_vec + k0 + akc);
    float4 w = *(const float4*)(Ws + (size_t)(k0 + bk) * DD + n0 + bn);
    float4 r;
    r.x = (a.x + b.x + v * c.x) * msk;
    r.y = (a.y + b.y + v * c.y) * msk;
    r.z = (a.z + b.z + v * c.z) * msk;
    r.w = (a.w + b.w + v * c.w) * msk;
    As[akc + 0][arow] = r.x;
    As[akc + 1][arow] = r.y;
    As[akc + 2][arow] = r.z;
    As[akc + 3][arow] = r.w;
    *(float4*)&Bs[bk][bn] = w;
    __syncthreads();
#pragma unroll
    for (int k = 0; k < 16; ++k) {
      const float4 av = *(const float4*)&As[k][ty << 2];
      const float4 bv = *(const float4*)&Bs[k][tx << 2];
      const float a4[4] = {av.x, av.y, av.z, av.w};
      const float b4[4] = {bv.x, bv.y, bv.z, bv.w};
#pragma unroll
      for (int i = 0; i < 4; ++i)
#pragma unroll
        for (int j = 0; j < 4; ++j)
          acc[i][j] = fmaf(a4[i], b4[j], acc[i][j]);
    }
    __syncthreads();
  }

  const float4 bsv = *(const float4*)(bs + n0 + (tx << 2));
#pragma unroll
  for (int i = 0; i < 4; ++i) {
    int gr = m0 + (ty << 2) + i;
    float4 o;
    o.x = gelu_f(acc[i][0] + bsv.x);
    o.y = gelu_f(acc[i][1] + bsv.y);
    o.z = gelu_f(acc[i][2] + bsv.z);
    o.w = gelu_f(acc[i][3] + bsv.w);
    *(float4*)(shared_out + (size_t)gr * DD + n0 + (tx << 2)) = o;
  }
}

// ---------------------------------------------------------------------------
// Stage 2: grouped head MLP. grid = (token-tile, F-chunk(256), head).
// Gathers up to 64 tokens of this head, computes hid = gelu(X@W1[h]+b1[h])
// for a 256-wide F chunk (K=1024), dots with W2[h] chunk, reduces across
// threads, atomicAdd partial into out[token].
// ---------------------------------------------------------------------------
__global__ __launch_bounds__(256) void gemm2_kernel(
    const float* __restrict__ shared_in, const float* __restrict__ W1,
    const float* __restrict__ b1, const float* __restrict__ W2,
    const int* __restrict__ counts, const int* __restrict__ lists,
    float* __restrict__ out) {
  const int h = blockIdx.z;
  const int nt = counts[h];
  const int m0 = blockIdx.x * 64;
  if (m0 >= nt) return;
  const int f0 = blockIdx.y * 256;

  __shared__ float As[16][64];    // [k][m]
  __shared__ float Bs[16][256];   // [k][f]
  __shared__ int   stok[64];
  __shared__ float red[64][17];   // +1 pad

  const int tid = threadIdx.x;
  if (tid < 64) {
    int i = m0 + tid;
    stok[tid] = (i < nt) ? lists[h * TOK + i] : -1;
  }
  __syncthreads();

  const int arow = tid >> 2;
  const int akc  = (tid & 3) << 2;
  const int tok  = stok[arow];
  const float* pa = shared_in + (size_t)tok * DD;   // only deref'd if tok>=0

  const int bk = tid >> 4;            // 0..15
  const int bn = (tid & 15) << 2;     // 0..60
  const float* w1h = W1 + (size_t)h * DD * FF;

  const int ty = tid >> 4;
  const int tx = tid & 15;

  float acc[4][16] = {};

  for (int k0 = 0; k0 < DD; k0 += 16) {
    float4 r = make_float4(0.f, 0.f, 0.f, 0.f);
    if (tok >= 0) r = *(const float4*)(pa + k0 + akc);
    const float* wrow = w1h + (size_t)(k0 + bk) * FF + f0 + bn;
    float4 w0 = *(const float4*)(wrow);
    float4 w1v = *(const float4*)(wrow + 64);
    float4 w2v = *(const float4*)(wrow + 128);
    float4 w3v = *(const float4*)(wrow + 192);
    As[akc + 0][arow] = r.x;
    As[akc + 1][arow] = r.y;
    As[akc + 2][arow] = r.z;
    As[akc + 3][arow] = r.w;
    *(float4*)&Bs[bk][bn]       = w0;
    *(float4*)&Bs[bk][bn + 64]  = w1v;
    *(float4*)&Bs[bk][bn + 128] = w2v;
    *(float4*)&Bs[bk][bn + 192] = w3v;
    __syncthreads();
#pragma unroll
    for (int k = 0; k < 16; ++k) {
      const float4 av = *(const float4*)&As[k][ty << 2];
      const float a4[4] = {av.x, av.y, av.z, av.w};
#pragma unroll
      for (int j = 0; j < 4; ++j) {
        const float4 bv = *(const float4*)&Bs[k][(tx << 2) + j * 64];
        const float b4[4] = {bv.x, bv.y, bv.z, bv.w};
#pragma unroll
        for (int i = 0; i < 4; ++i)
#pragma unroll
          for (int jj = 0; jj < 4; ++jj)
            acc[i][j * 4 + jj] = fmaf(a4[i], b4[jj], acc[i][j * 4 + jj]);
      }
    }
    __syncthreads();
  }

  // Epilogue: +b1, gelu, dot with W2 chunk.
  float rowsum[4] = {};
  const float* b1h = b1 + (size_t)h * FF;
  const float* w2h = W2 + (size_t)h * FF;
#pragma unroll
  for (int j = 0; j < 4; ++j) {
    int col = f0 + (tx << 2) + j * 64;
    const float4 b1v = *(const float4*)(b1h + col);
    const float4 w2v = *(const float4*)(w2h + col);
    const float b14[4] = {b1v.x, b1v.y, b1v.z, b1v.w};
    const float w24[4] = {w2v.x, w2v.y, w2v.z, w2v.w};
#pragma unroll
    for (int i = 0; i < 4; ++i)
#pragma unroll
      for (int jj = 0; jj < 4; ++jj)
        rowsum[i] += gelu_f(acc[i][j * 4 + jj] + b14[jj]) * w24[jj];
  }

#pragma unroll
  for (int i = 0; i < 4; ++i) red[(ty << 2) + i][tx] = rowsum[i];
  __syncthreads();

  if (tid < 64) {
    if (m0 + tid < nt) {
      float s = 0.f;
#pragma unroll
      for (int j = 0; j < 16; ++j) s += red[tid][j];
      atomicAdd(&out[stok[tid]], s);
    }
  }
}

// ---------------------------------------------------------------------------
extern "C" void kernel_launch(void* const* d_in, const int* in_sizes, int n_in,
                              void* d_out, int out_size, void* d_ws, size_t ws_size,
                              hipStream_t stream) {
  const int*   selfies = (const int*)d_in[0];
  const int*   tasks   = (const int*)d_in[1];
  const float* values  = (const float*)d_in[2];
  const int*   pmask   = (const int*)d_in[3];
  const float* emb_s   = (const float*)d_in[4];
  const float* emb_t   = (const float*)d_in[5];
  const float* val_vec = (const float*)d_in[6];
  const float* Ws      = (const float*)d_in[7];
  const float* bs      = (const float*)d_in[8];
  const float* W1      = (const float*)d_in[9];
  const float* b1      = (const float*)d_in[10];
  const float* W2      = (const float*)d_in[11];
  const float* b2      = (const float*)d_in[12];
  float* out = (float*)d_out;

  // Workspace layout: shared[4096x1024] f32 (16 MB) | counts (64 B, 256-aligned) | lists (256 KB)
  char* ws = (char*)d_ws;
  float* shared_buf = (float*)ws;
  size_t off = (size_t)TOK * DD * sizeof(float);
  int* counts = (int*)(ws + off);
  int* lists  = (int*)(ws + off + 256);

  hipMemsetAsync(counts, 0, NH * sizeof(int), stream);
  route_kernel<<<TOK / 256, 256, 0, stream>>>(tasks, b2, counts, lists, out);
  gemm1_kernel<<<dim3(TOK / 64, DD / 64), 256, 0, stream>>>(
      selfies, tasks, values, pmask, emb_s, emb_t, val_vec, Ws, bs, shared_buf);
  gemm2_kernel<<<dim3(TOK / 64, FF / 256, NH), 256, 0, stream>>>(
      shared_buf, W1, b1, W2, counts, lists, out);
}

// Round 2
// 354.123 us; speedup vs baseline: 4.7747x; 4.7747x over previous
//
#include <hip/hip_runtime.h>
#include <hip/hip_bf16.h>

// B=8, S=512 -> TOK=4096 tokens, D=1024, F=2048, H=16 heads, O=1.
#define TOK 4096
#define DD  1024
#define FF  2048
#define NH  16

typedef short bf16x8 __attribute__((ext_vector_type(8)));
typedef float f32x4  __attribute__((ext_vector_type(4)));

__device__ __forceinline__ float gelu_f(float x) {
  float u = 0.7978845608028654f * (x + 0.044715f * x * x * x);
  float e = __expf(2.0f * u);
  return 0.5f * x * (2.0f - 2.0f / (e + 1.0f));
}

// fp32 -> bf16 round-to-nearest-even
__device__ __forceinline__ unsigned short f2bf(float f) {
  union { float f; unsigned u; } v; v.f = f;
  unsigned r = v.u + 0x7FFF + ((v.u >> 16) & 1);
  return (unsigned short)(r >> 16);
}
__device__ __forceinline__ unsigned pack2(float a, float b) {
  return (unsigned)f2bf(a) | ((unsigned)f2bf(b) << 16);
}

// async global->LDS, 16 bytes per lane; LDS dst = wave-uniform base + lane*16
__device__ __forceinline__ void load_lds16(const void* g, void* l) {
  __builtin_amdgcn_global_load_lds(
      (const __attribute__((address_space(1))) void*)g,
      (__attribute__((address_space(3))) void*)l, 16, 0, 0);
}

// ---------------------------------------------------------------------------
// Routing: head = (task-1)&15 for task>0 else invalid. Builds per-head token
// lists; initializes out with b2[h] (stage-2 atomically adds) or 0.
// ---------------------------------------------------------------------------
__global__ __launch_bounds__(256) void route_kernel(
    const int* __restrict__ tasks, const float* __restrict__ b2,
    int* __restrict__ counts, int* __restrict__ lists, float* __restrict__ out) {
  int t = blockIdx.x * 256 + threadIdx.x;
  if (t >= TOK) return;
  int task = tasks[t];
  if (task > 0) {
    int h = (task - 1) & (NH - 1);
    int pos = atomicAdd(&counts[h], 1);
    lists[h * TOK + pos] = t;
    out[t] = b2[h];
  } else {
    out[t] = 0.0f;
  }
}

// ---------------------------------------------------------------------------
// prep_x: X[t][k] = (emb_s[sid]+emb_t[tsk]+v*val_vec)*mask -> bf16 row-major.
// One thread per 8-element chunk (t, kc). Fully coalesced.
// ---------------------------------------------------------------------------
__global__ __launch_bounds__(256) void prep_x(
    const int* __restrict__ selfies, const int* __restrict__ tasks,
    const float* __restrict__ values, const int* __restrict__ pmask,
    const float* __restrict__ emb_s, const float* __restrict__ emb_t,
    const float* __restrict__ val_vec, unsigned short* __restrict__ Xb) {
  int gid = blockIdx.x * 256 + threadIdx.x;   // TOK*128 threads
  int kc = (gid & 127) * 8;
  int t  = gid >> 7;
  int sid = selfies[t], tsk = tasks[t];
  float v = values[t];
  float msk = pmask[t] ? 1.0f : 0.0f;
  const float* ps = emb_s + (size_t)sid * DD + kc;
  const float* pt = emb_t + (size_t)tsk * DD + kc;
  const float* pv = val_vec + kc;
  float r[8];
#pragma unroll
  for (int j = 0; j < 8; j += 4) {
    float4 a = *(const float4*)(ps + j);
    float4 b = *(const float4*)(pt + j);
    float4 c = *(const float4*)(pv + j);
    r[j + 0] = (a.x + b.x + v * c.x) * msk;
    r[j + 1] = (a.y + b.y + v * c.y) * msk;
    r[j + 2] = (a.z + b.z + v * c.z) * msk;
    r[j + 3] = (a.w + b.w + v * c.w) * msk;
  }
  uint4 o;
  o.x = pack2(r[0], r[1]); o.y = pack2(r[2], r[3]);
  o.z = pack2(r[4], r[5]); o.w = pack2(r[6], r[7]);
  *(uint4*)(Xb + (size_t)gid * 8) = o;
}

// ---------------------------------------------------------------------------
// prep_w: transpose+pack Ws and W1 (fp32 k-major) into bf16 MFMA-frag-major:
//   dst[(mat_tile nt)*32 + kc2][lane=q*16+nn][j] = W[kc2*32+q*8+j][nt*16+nn]
// One thread per 16-B output chunk; 8 strided fp32 reads, 1 uint4 store.
// W1p region: cid < 16*128*32*64 ; Wsp region: next 64*32*64.
// ---------------------------------------------------------------------------
__global__ __launch_bounds__(256) void prep_w(
    const float* __restrict__ Ws, const float* __restrict__ W1,
    unsigned short* __restrict__ Wsp, unsigned short* __restrict__ W1p) {
  int cid = blockIdx.x * 256 + threadIdx.x;
  const float* src;
  unsigned short* dst;
  int stride;
  if (cid < 16 * 128 * 32 * 64) {
    int lane = cid & 63, kc2 = (cid >> 6) & 31, nt = (cid >> 11) & 127, h = cid >> 18;
    src = W1 + ((size_t)h * DD + kc2 * 32 + (lane >> 4) * 8) * FF + nt * 16 + (lane & 15);
    dst = W1p + (size_t)cid * 8;
    stride = FF;
  } else {
    int cid2 = cid - 16 * 128 * 32 * 64;   // < 64*32*64
    int lane = cid2 & 63, kc2 = (cid2 >> 6) & 31, nt = cid2 >> 11;
    src = Ws + ((size_t)kc2 * 32 + (lane >> 4) * 8) * DD + nt * 16 + (lane & 15);
    dst = Wsp + (size_t)cid2 * 8;
    stride = DD;
  }
  float r[8];
#pragma unroll
  for (int j = 0; j < 8; ++j) r[j] = src[(size_t)j * stride];
  uint4 o;
  o.x = pack2(r[0], r[1]); o.y = pack2(r[2], r[3]);
  o.z = pack2(r[4], r[5]); o.w = pack2(r[6], r[7]);
  *(uint4*)dst = o;
}

// ---------------------------------------------------------------------------
// Stage 1: shared = gelu(X @ Ws + bs) in bf16 MFMA. Block = 64m x 128n,
// BK=64, 4 waves, wave = 64m x 32n (4 mt x 2 nt tiles). grid (64, 8).
// ---------------------------------------------------------------------------
__global__ __launch_bounds__(256) void gemm1_mfma(
    const unsigned short* __restrict__ Xb, const unsigned short* __restrict__ Wsp,
    const float* __restrict__ bs, unsigned short* __restrict__ shared_bf) {
  __shared__ __align__(16) unsigned short As[2 * 4 * 64 * 8];   // 8 KB
  __shared__ __align__(16) unsigned short Bs[2 * 8 * 64 * 8];   // 16 KB

  const int tid = threadIdx.x;
  const int lane = tid & 63, w = tid >> 6;
  const int m0 = blockIdx.x * 64;
  const int n0 = blockIdx.y * 128;
  const int q = lane >> 4, c = lane & 15;

  // A staging: wave w stages rows m0 + w*16 + c, k-chunks (kk*4+q)*8
  const unsigned short* aSrc = Xb + (size_t)(m0 + w * 16 + c) * DD + q * 8;
  unsigned short* aDst0 = As + (size_t)(0 * 256 + w * 64 + lane) * 8;
  unsigned short* aDst1 = As + (size_t)(1 * 256 + w * 64 + lane) * 8;

  // B staging: wave w stages nt = w*2+{0,1}, kk={0,1}
  const unsigned short* bBase = Wsp + ((size_t)(blockIdx.y * 8 + w * 2)) * 32 * 512 + lane * 8;
  f32x4 acc[4][2] = {};

  for (int k0 = 0; k0 < DD; k0 += 64) {
    load_lds16(aSrc + k0, aDst0);
    load_lds16(aSrc + k0 + 32, aDst1);
    const unsigned short* bk = bBase + k0 * 16;
#pragma unroll
    for (int i = 0; i < 4; ++i) {
      int kk = i >> 1, t = i & 1;
      load_lds16(bk + (size_t)t * 16384 + kk * 512,
                 Bs + (size_t)(kk * 8 + w * 2 + t) * 512 + lane * 8);
    }
    __syncthreads();
#pragma unroll
    for (int kk = 0; kk < 2; ++kk) {
      bf16x8 a[4], b[2];
#pragma unroll
      for (int mt = 0; mt < 4; ++mt)
        a[mt] = *(const bf16x8*)(As + (size_t)((kk * 4 + mt) * 64 + lane) * 8);
#pragma unroll
      for (int t = 0; t < 2; ++t)
        b[t] = *(const bf16x8*)(Bs + (size_t)((kk * 8 + w * 2 + t) * 64 + lane) * 8);
#pragma unroll
      for (int mt = 0; mt < 4; ++mt)
#pragma unroll
        for (int t = 0; t < 2; ++t)
          acc[mt][t] = __builtin_amdgcn_mfma_f32_16x16x32_bf16(a[mt], b[t], acc[mt][t], 0, 0, 0);
    }
    __syncthreads();
  }

  // Epilogue: +bs, gelu, bf16, scatter u16 stores (C: row=mt*16+q*4+r, col=nt*16+c)
  float bsv[2];
#pragma unroll
  for (int t = 0; t < 2; ++t) bsv[t] = bs[n0 + w * 32 + t * 16 + c];
#pragma unroll
  for (int mt = 0; mt < 4; ++mt)
#pragma unroll
    for (int t = 0; t < 2; ++t)
#pragma unroll
      for (int r = 0; r < 4; ++r) {
        int row = m0 + mt * 16 + q * 4 + r;
        int col = n0 + w * 32 + t * 16 + c;
        shared_bf[(size_t)row * DD + col] = f2bf(gelu_f(acc[mt][t][r] + bsv[t]));
      }
}

// ---------------------------------------------------------------------------
// Stage 2: per-head MLP. Block = 64 tokens x 256 F, BK=64, 4 waves,
// wave = 64m x 64n (4 mt x 4 nt). grid (8 token-tiles, 8 f-chunks, 16 heads).
// Epilogue: gelu(+b1) dot W2-chunk, shuffle+LDS reduce, atomicAdd into out.
// ---------------------------------------------------------------------------
__global__ __launch_bounds__(256) void gemm2_mfma(
    const unsigned short* __restrict__ shared_bf, const unsigned short* __restrict__ W1p,
    const float* __restrict__ b1, const float* __restrict__ W2,
    const int* __restrict__ counts, const int* __restrict__ lists,
    float* __restrict__ out) {
  const int h = blockIdx.z;
  const int nt_h = counts[h];
  const int m0 = blockIdx.x * 64;
  if (m0 >= nt_h) return;
  const int fc = blockIdx.y;             // f0 = fc*256

  __shared__ __align__(16) unsigned short As[2 * 4 * 64 * 8];    // 8 KB
  __shared__ __align__(16) unsigned short Bs[2 * 16 * 64 * 8];   // 32 KB
  __shared__ int   stok[64];
  __shared__ float red[4][68];

  const int tid = threadIdx.x;
  const int lane = tid & 63, w = tid >> 6;
  const int q = lane >> 4, c = lane & 15;

  if (tid < 64) {
    int i = m0 + tid;
    stok[tid] = (i < nt_h) ? lists[h * TOK + i] : -1;
  }
  __syncthreads();

  // A staging (gathered rows; dead rows read token row of stok clamped to 0 --
  // their accumulator rows are discarded in the epilogue).
  int tokr = stok[w * 16 + c];
  if (tokr < 0) tokr = 0;
  const unsigned short* aSrc = shared_bf + (size_t)tokr * DD + q * 8;
  unsigned short* aDst0 = As + (size_t)(0 * 256 + w * 64 + lane) * 8;
  unsigned short* aDst1 = As + (size_t)(1 * 256 + w * 64 + lane) * 8;

  // B staging: wave w stages nt = w*4+{0..3}, kk={0,1}
  const unsigned short* bBase =
      W1p + ((size_t)h * 128 + fc * 16 + w * 4) * 32 * 512 + lane * 8;

  f32x4 acc[4][4] = {};

  for (int k0 = 0; k0 < DD; k0 += 64) {
    load_lds16(aSrc + k0, aDst0);
    load_lds16(aSrc + k0 + 32, aDst1);
    const unsigned short* bk = bBase + k0 * 16;
#pragma unroll
    for (int i = 0; i < 8; ++i) {
      int kk = i >> 2, t = i & 3;
      load_lds16(bk + (size_t)t * 16384 + kk * 512,
                 Bs + (size_t)(kk * 16 + w * 4 + t) * 512 + lane * 8);
    }
    __syncthreads();
#pragma unroll
    for (int kk = 0; kk < 2; ++kk) {
      bf16x8 a[4], b[4];
#pragma unroll
      for (int mt = 0; mt < 4; ++mt)
        a[mt] = *(const bf16x8*)(As + (size_t)((kk * 4 + mt) * 64 + lane) * 8);
#pragma unroll
      for (int t = 0; t < 4; ++t)
        b[t] = *(const bf16x8*)(Bs + (size_t)((kk * 16 + w * 4 + t) * 64 + lane) * 8);
#pragma unroll
      for (int mt = 0; mt < 4; ++mt)
#pragma unroll
        for (int t = 0; t < 4; ++t)
          acc[mt][t] = __builtin_amdgcn_mfma_f32_16x16x32_bf16(a[mt], b[t], acc[mt][t], 0, 0, 0);
    }
    __syncthreads();
  }

  // Epilogue: per lane cols n = fc*256 + w*64 + t*16 + c
  const float* b1h = b1 + (size_t)h * FF + fc * 256 + w * 64;
  const float* w2h = W2 + (size_t)h * FF + fc * 256 + w * 64;
  float b1v[4], w2v[4];
#pragma unroll
  for (int t = 0; t < 4; ++t) { b1v[t] = b1h[t * 16 + c]; w2v[t] = w2h[t * 16 + c]; }

#pragma unroll
  for (int mt = 0; mt < 4; ++mt)
#pragma unroll
    for (int r = 0; r < 4; ++r) {
      float s = 0.0f;
#pragma unroll
      for (int t = 0; t < 4; ++t)
        s += gelu_f(acc[mt][t][r] + b1v[t]) * w2v[t];
      s += __shfl_xor(s, 1);
      s += __shfl_xor(s, 2);
      s += __shfl_xor(s, 4);
      s += __shfl_xor(s, 8);
      if (c == 0) red[w][mt * 16 + q * 4 + r] = s;
    }
  __syncthreads();

  if (tid < 64) {
    int t = stok[tid];
    if (t >= 0) {
      float s = red[0][tid] + red[1][tid] + red[2][tid] + red[3][tid];
      atomicAdd(&out[t], s);
    }
  }
}

// ---------------------------------------------------------------------------
extern "C" void kernel_launch(void* const* d_in, const int* in_sizes, int n_in,
                              void* d_out, int out_size, void* d_ws, size_t ws_size,
                              hipStream_t stream) {
  const int*   selfies = (const int*)d_in[0];
  const int*   tasks   = (const int*)d_in[1];
  const float* values  = (const float*)d_in[2];
  const int*   pmask   = (const int*)d_in[3];
  const float* emb_s   = (const float*)d_in[4];
  const float* emb_t   = (const float*)d_in[5];
  const float* val_vec = (const float*)d_in[6];
  const float* Ws      = (const float*)d_in[7];
  const float* bs      = (const float*)d_in[8];
  const float* W1      = (const float*)d_in[9];
  const float* b1      = (const float*)d_in[10];
  const float* W2      = (const float*)d_in[11];
  const float* b2      = (const float*)d_in[12];
  float* out = (float*)d_out;

  // Workspace layout (all 256-B aligned):
  //   Xb        bf16 [4096][1024]            8 MB
  //   shared_bf bf16 [4096][1024]            8 MB
  //   Wsp       bf16 frag-major              2 MB
  //   W1p       bf16 frag-major             64 MB
  //   counts    int[16] ; lists int[16*4096]
  char* ws = (char*)d_ws;
  unsigned short* Xb        = (unsigned short*)ws;
  unsigned short* shared_bf = (unsigned short*)(ws + (8u << 20));
  unsigned short* Wsp       = (unsigned short*)(ws + (16u << 20));
  unsigned short* W1p       = (unsigned short*)(ws + (18u << 20));
  int* counts = (int*)(ws + (82u << 20));
  int* lists  = (int*)(ws + (82u << 20) + 256);

  hipMemsetAsync(counts, 0, NH * sizeof(int), stream);
  route_kernel<<<TOK / 256, 256, 0, stream>>>(tasks, b2, counts, lists, out);
  prep_x<<<TOK * 128 / 256, 256, 0, stream>>>(selfies, tasks, values, pmask,
                                              emb_s, emb_t, val_vec, Xb);
  prep_w<<<(16 * 128 * 32 * 64 + 64 * 32 * 64) / 256, 256, 0, stream>>>(Ws, W1, Wsp, W1p);
  gemm1_mfma<<<dim3(TOK / 64, DD / 128), 256, 0, stream>>>(Xb, Wsp, bs, shared_bf);
  gemm2_mfma<<<dim3(8, FF / 256, NH), 256, 0, stream>>>(shared_bf, W1p, b1, W2,
                                                        counts, lists, out);
}